// Round 8
// baseline (775.150 us; speedup 1.0000x reference)
//
#include <hip/hip_runtime.h>
#include <hip/hip_bf16.h>
#include <cstdint>

#define NM 20

typedef __attribute__((ext_vector_type(8))) short bf16x8;
typedef __attribute__((ext_vector_type(4))) float f32x4;
typedef __attribute__((ext_vector_type(4))) unsigned int u32x4;

union FU { bf16x8 h; u32x4 u; };

#define MFMA(A, Bf, C) __builtin_amdgcn_mfma_f32_16x16x32_bf16((A), (Bf), (C), 0, 0, 0)

// A-fragment-packed, ROW-PERMUTED weights (bf16), built by prep each launch.
#define F_NE    0        // 4 frags  (4mb x 1kc, K=16 pad 32)
#define F_M1W1  2048     // 16       (4mb x 4kc, K=128)
#define F_M1W2  10240    // 8        (4mb x 2kc)
#define F_M2W1  14336    // 16
#define F_M2W2  22528    // 8
#define F_WIH   26624    // 36       (12mb x 3kc, K=72 pad 96)
#define F_WHH   45056    // 24       (12mb x 2kc)
#define F_PQ    57344    // 8        (identity rows)
#define F_PK    61440    // 8        (identity rows)
#define F_PACK  65536    // 4        (2mb x 2kc, rows = op|c1|c2 pad 32)
// bf16-packed bias/LN vectors (natural feature order, 64 each)
#define F_BNE   67584
#define F_B11   67648
#define F_B12   67712
#define F_G1    67776
#define F_L1    67840
#define F_B21   67904
#define F_B22   67968
#define F_G2    68032
#define F_L2    68096
#define F_TOTAL 68160

__device__ __align__(16) short g_fr[F_TOTAL];

__device__ __forceinline__ short bf16rn(float x) {
  unsigned u = __float_as_uint(x);
  u += 0x7fffu + ((u >> 16) & 1u);
  return (short)(u >> 16);
}
__device__ __forceinline__ float bf2f(short s) {
  return __uint_as_float(((unsigned)(unsigned short)s) << 16);
}
__device__ __forceinline__ unsigned pk2(float lo, float hi) {
  __hip_bfloat162 t = __float22bfloat162_rn(float2{lo, hi});
  return *reinterpret_cast<unsigned*>(&t);
}
__device__ __forceinline__ int s64(int r) {
  int mb = r >> 4, qq = (r >> 2) & 3, i = r & 3;
  return (mb >> 1) * 32 + qq * 8 + (mb & 1) * 4 + i;
}

#define LDF(off) (*(const bf16x8*)(g_fr + (off) + lane * 8))
#define LDB(off, c) (*(const bf16x8*)(g_fr + (off) + (c) * 32 + q * 8))

// ---------------- prep ----------------
#define BUILDA(OFS, MB, KC, ROWX, GET)                                 \
  for (int idx = t; idx < (MB) * (KC) * 512; idx += T) {               \
    int j = idx & 7, ln = (idx >> 3) & 63, f = idx >> 9;               \
    int mb = f / (KC), kc = f % (KC);                                  \
    int m = mb * 16 + (ln & 15);                                       \
    int k = kc * 32 + (ln >> 4) * 8 + j;                               \
    int row = (ROWX);                                                  \
    (void)row; (void)k; (void)m;                                       \
    g_fr[(OFS) + idx] = bf16rn(GET);                                   \
  }

__global__ void __launch_bounds__(256)
prep_frag(const float* __restrict__ ne_w,
          const float* __restrict__ m1w1, const float* __restrict__ m1w2,
          const float* __restrict__ m2w1, const float* __restrict__ m2w2,
          const float* __restrict__ wih,  const float* __restrict__ whh,
          const float* __restrict__ pqw,  const float* __restrict__ opw,
          const float* __restrict__ c1w,  const float* __restrict__ c2w,
          const float* __restrict__ pkw,
          const float* __restrict__ ne_b,
          const float* __restrict__ m1b1, const float* __restrict__ m1b2,
          const float* __restrict__ n1g,  const float* __restrict__ n1b,
          const float* __restrict__ m2b1, const float* __restrict__ m2b2,
          const float* __restrict__ n2g,  const float* __restrict__ n2b,
          int* __restrict__ ws)
{
  const int t = blockIdx.x * blockDim.x + threadIdx.x;
  const int T = gridDim.x * blockDim.x;
  if (t < 64) ws[t] = 0;   // hist[0..31] + cursor[32..63] zeroed
  BUILDA(F_NE,   4, 1, s64(m), (k < 16 ? ne_w[row * 16 + k] : 0.f))
  BUILDA(F_M1W1, 4, 4, s64(m), m1w1[row * 128 + k])
  BUILDA(F_M1W2, 4, 2, s64(m), m1w2[row * 64 + k])
  BUILDA(F_M2W1, 4, 4, s64(m), m2w1[row * 128 + k])
  BUILDA(F_M2W2, 4, 2, s64(m), m2w2[row * 64 + k])
  BUILDA(F_WIH, 12, 3, (m & 0xC0) | s64(m & 63), (k < 72 ? wih[row * 72 + k] : 0.f))
  BUILDA(F_WHH, 12, 2, (m & 0xC0) | s64(m & 63), whh[row * 64 + k])
  BUILDA(F_PQ,   4, 2, m, pqw[row * 64 + k])
  BUILDA(F_PK,   4, 2, m, pkw[row * 64 + k])
  BUILDA(F_PACK, 2, 2, m, (row < 8 ? opw[row * 64 + k]
                           : row < 18 ? c1w[(row - 8) * 64 + k]
                           : row < 28 ? c2w[(row - 18) * 64 + k] : 0.f))
  for (int i = t; i < 64; i += T) {
    g_fr[F_BNE + i] = bf16rn(ne_b[i]);
    g_fr[F_B11 + i] = bf16rn(m1b1[i]);
    g_fr[F_B12 + i] = bf16rn(m1b2[i]);
    g_fr[F_G1  + i] = bf16rn(n1g[i]);
    g_fr[F_L1  + i] = bf16rn(n1b[i]);
    g_fr[F_B21 + i] = bf16rn(m2b1[i]);
    g_fr[F_B22 + i] = bf16rn(m2b2[i]);
    g_fr[F_G2  + i] = bf16rn(n2g[i]);
    g_fr[F_L2  + i] = bf16rn(n2b[i]);
  }
}

// ---------------- counting sort of batches by n_nodes ----------------
__global__ void __launch_bounds__(256)
sort_hist(const int* __restrict__ nnp, int* __restrict__ ws, int B) {
  int b = blockIdx.x * blockDim.x + threadIdx.x;
  if (b < B) atomicAdd(&ws[nnp[b] - 1], 1);
}
__global__ void __launch_bounds__(64)
sort_scan(int* __restrict__ ws) {
  if (threadIdx.x == 0) {
    int acc = 0;
    for (int i = 0; i < NM; i++) { ws[32 + i] = acc; acc += ws[i]; }
  }
}
__global__ void __launch_bounds__(256)
sort_scatter(const int* __restrict__ nnp, int* __restrict__ ws, int B) {
  int b = blockIdx.x * blockDim.x + threadIdx.x;
  if (b < B) {
    int nn = nnp[b];
    int pos = atomicAdd(&ws[32 + nn - 1], 1);
    ws[64 + pos] = b;          // perm
    ws[64 + B + pos] = nn;     // nn sorted
  }
}

__device__ __forceinline__ void pack8(FU& f, const float* v) {
  f.u[0] = pk2(v[0], v[1]); f.u[1] = pk2(v[2], v[3]);
  f.u[2] = pk2(v[4], v[5]); f.u[3] = pk2(v[6], v[7]);
}

// ---------------- MP stage: nodes n = wv + 4t, capped at Mcap ----------------
__device__ __forceinline__ void mp_stage(
    FU hA[][2], float* macc_out, const FU* msgf,
    int w1off, int w2off, int b1o, int b2o, int lgo, int lbo,
    int nnv, int Mcap, int wv, int lane, int q)
{
  const f32x4 zf4 = {0.f, 0.f, 0.f, 0.f};
  bf16x8 w1A[4][2], w2A[4][2];
  #pragma unroll
  for (int mb = 0; mb < 4; mb++) {
    w1A[mb][0] = LDF(w1off + (mb * 4 + 0) * 512);
    w1A[mb][1] = LDF(w1off + (mb * 4 + 1) * 512);
    w2A[mb][0] = LDF(w2off + (mb * 2 + 0) * 512);
    w2A[mb][1] = LDF(w2off + (mb * 2 + 1) * 512);
  }
  f32x4 tmsg[4];
  #pragma unroll
  for (int mb = 0; mb < 4; mb++) {
    tmsg[mb] = MFMA(LDF(w1off + (mb * 4 + 2) * 512), msgf[0].h, zf4);
    tmsg[mb] = MFMA(LDF(w1off + (mb * 4 + 3) * 512), msgf[1].h, tmsg[mb]);
  }
  FU b1p[2], b2p[2], lgp[2], lbp[2];
  #pragma unroll
  for (int c = 0; c < 2; c++) {
    b1p[c].h = LDB(b1o, c); b2p[c].h = LDB(b2o, c);
    lgp[c].h = LDB(lgo, c); lbp[c].h = LDB(lbo, c);
  }

  #pragma unroll
  for (int t = 0; t < 5; t++) {
    const int n = wv + 4 * t;
    if (n >= Mcap) break;           // wave-uniform cap (sorted batches)
    f32x4 T[4];
    #pragma unroll
    for (int mb = 0; mb < 4; mb++) {
      T[mb] = MFMA(w1A[mb][0], hA[t][0].h, tmsg[mb]);
      T[mb] = MFMA(w1A[mb][1], hA[t][1].h, T[mb]);
    }
    FU tb[2];
    #pragma unroll
    for (int c = 0; c < 2; c++)
      #pragma unroll
      for (int w = 0; w < 4; w++) {
        int mb = 2 * c + (w >> 1), i0 = (w & 1) * 2;
        float blo = bf2f(b1p[mb >> 1].h[(mb & 1) * 4 + i0]);
        float bhi = bf2f(b1p[mb >> 1].h[(mb & 1) * 4 + i0 + 1]);
        float lo = fmaxf(T[mb][i0]     + blo, 0.f);
        float hi = fmaxf(T[mb][i0 + 1] + bhi, 0.f);
        tb[c].u[w] = pk2(lo, hi);
      }
    f32x4 H[4];
    #pragma unroll
    for (int mb = 0; mb < 4; mb++) {
      H[mb] = MFMA(w2A[mb][0], tb[0].h, zf4);
      H[mb] = MFMA(w2A[mb][1], tb[1].h, H[mb]);
    }
    float y[16]; float s = 0.f, ss = 0.f;
    #pragma unroll
    for (int k = 0; k < 16; k++) {
      int c = k >> 3, j = k & 7;
      float v = H[2 * c + (j >> 2)][j & 3] + bf2f(b2p[c].h[j]) + bf2f(hA[t][c].h[j]);
      y[k] = v; s += v; ss += v * v;
    }
    s += __shfl_xor(s, 16, 64); ss += __shfl_xor(ss, 16, 64);
    s += __shfl_xor(s, 32, 64); ss += __shfl_xor(ss, 32, 64);
    float mu = s * 0.015625f;
    float rstd = rsqrtf(ss * 0.015625f - mu * mu + 1e-5f);
    float mfv = (n < nnv) ? 1.f : 0.f;
    #pragma unroll
    for (int k = 0; k < 16; k++) {
      int c = k >> 3, j = k & 7;
      float hv = ((y[k] - mu) * rstd * bf2f(lgp[c].h[j]) + bf2f(lbp[c].h[j])) * mfv;
      macc_out[k] += hv; y[k] = hv;
    }
    pack8(hA[t][0], y); pack8(hA[t][1], y + 8);
  }
}

// ---------------- main: 16 sorted batches / block, stride-4 node interleave ----------------
__global__ void __launch_bounds__(256)
msp(const float* __restrict__ nf, const int* __restrict__ wsp,
    const float* __restrict__ rnn, const float* __restrict__ poh,
    const float* __restrict__ bih, const float* __restrict__ bhh,
    const float* __restrict__ opb, const float* __restrict__ c1b,
    const float* __restrict__ c2b, const float* __restrict__ pqb,
    const float* __restrict__ pkb,
    float* __restrict__ out, int B)
{
  __shared__ __align__(16) float exch[2][4][64][17];   // 34816 B
  __shared__ __align__(16) unsigned nsx[64][8];        // 2048 B

  const int tid = threadIdx.x;
  const int wv = tid >> 6;
  const int lane = tid & 63;
  const int l15 = lane & 15, q = lane >> 4;
  const int pos = blockIdx.x * 16 + l15;

  const int bb  = wsp[64 + pos];        // perm
  const int nnv = wsp[64 + B + pos];    // sorted nn
  int mx = nnv;
  mx = max(mx, __shfl_xor(mx, 1, 64));
  mx = max(mx, __shfl_xor(mx, 2, 64));
  mx = max(mx, __shfl_xor(mx, 4, 64));
  mx = max(mx, __shfl_xor(mx, 8, 64));
  const int Mcap = mx;                  // uniform across the whole block

  const float inv = 1.0f / (float)nnv;
  const f32x4 zf4 = {0.f, 0.f, 0.f, 0.f};

  FU hA[5][2];
  float mac[16];
  #pragma unroll
  for (int k = 0; k < 16; k++) mac[k] = 0.f;

  // ================= E: h0^T = ne_w' · x^T =================
  {
    bf16x8 neA[4];
    #pragma unroll
    for (int mb = 0; mb < 4; mb++) neA[mb] = LDF(F_NE + mb * 512);
    FU nep[2];
    nep[0].h = LDB(F_BNE, 0); nep[1].h = LDB(F_BNE, 1);
    #pragma unroll
    for (int t = 0; t < 5; t++) {
      const int n = wv + 4 * t;
      if (n >= Mcap) break;
      FU bx;
      if (q < 2) {
        const float* p = nf + ((size_t)bb * NM + n) * 16 + q * 8;
        float4 x0 = *(const float4*)p, x1 = *(const float4*)(p + 4);
        bx.u[0] = pk2(x0.x, x0.y); bx.u[1] = pk2(x0.z, x0.w);
        bx.u[2] = pk2(x1.x, x1.y); bx.u[3] = pk2(x1.z, x1.w);
      } else {
        bx.u[0] = 0; bx.u[1] = 0; bx.u[2] = 0; bx.u[3] = 0;
      }
      f32x4 C[4];
      #pragma unroll
      for (int mb = 0; mb < 4; mb++) C[mb] = MFMA(neA[mb], bx.h, zf4);
      float hv[16];
      #pragma unroll
      for (int k = 0; k < 16; k++) {
        int c = k >> 3, j = k & 7;
        hv[k] = C[2 * c + (j >> 2)][j & 3] + bf2f(nep[c].h[j]);
        if (n < nnv) mac[k] += hv[k];
      }
      pack8(hA[t][0], hv); pack8(hA[t][1], hv + 8);
    }
  }

  FU msgf[2];
  float tmp[16];
  #define EXCHANGE(REG)                                                        \
    _Pragma("unroll")                                                          \
    for (int k = 0; k < 16; k++) exch[REG][wv][lane][k] = mac[k];              \
    __syncthreads();                                                           \
    _Pragma("unroll")                                                          \
    for (int k = 0; k < 16; k++)                                               \
      tmp[k] = (exch[REG][0][lane][k] + exch[REG][1][lane][k] +                \
                exch[REG][2][lane][k] + exch[REG][3][lane][k]) * inv;

  EXCHANGE(0)   // msg1
  pack8(msgf[0], tmp); pack8(msgf[1], tmp + 8);
  #pragma unroll
  for (int k = 0; k < 16; k++) mac[k] = 0.f;
  mp_stage(hA, mac, msgf, F_M1W1, F_M1W2, F_B11, F_B12, F_G1, F_L1, nnv, Mcap, wv, lane, q);

  EXCHANGE(1)   // msg2
  pack8(msgf[0], tmp); pack8(msgf[1], tmp + 8);
  #pragma unroll
  for (int k = 0; k < 16; k++) mac[k] = 0.f;
  mp_stage(hA, mac, msgf, F_M2W1, F_M2W2, F_B21, F_B22, F_G2, F_L2, nnv, Mcap, wv, lane, q);

  EXCHANGE(0)   // graph_vec

  // ================= GRU: wave wv owns gate tile tt = wv =================
  {
    FU gx[2]; pack8(gx[0], tmp); pack8(gx[1], tmp + 8);
    FU px;
    if (q == 0) {
      const float* pp = poh + (size_t)bb * 8;
      float4 p0 = *(const float4*)pp, p1 = *(const float4*)(pp + 4);
      px.u[0] = pk2(p0.x, p0.y); px.u[1] = pk2(p0.z, p0.w);
      px.u[2] = pk2(p1.x, p1.y); px.u[3] = pk2(p1.z, p1.w);
    } else { px.u[0] = 0; px.u[1] = 0; px.u[2] = 0; px.u[3] = 0; }
    const float* rr0 = rnn + (size_t)bb * 64;
    float rv[16];
    #pragma unroll
    for (int c = 0; c < 2; c++) {
      float4 a0 = *(const float4*)(rr0 + c * 32 + q * 8);
      float4 a1 = *(const float4*)(rr0 + c * 32 + q * 8 + 4);
      rv[c * 8 + 0] = a0.x; rv[c * 8 + 1] = a0.y; rv[c * 8 + 2] = a0.z; rv[c * 8 + 3] = a0.w;
      rv[c * 8 + 4] = a1.x; rv[c * 8 + 5] = a1.y; rv[c * 8 + 6] = a1.z; rv[c * 8 + 7] = a1.w;
    }
    FU ah[2]; pack8(ah[0], rv); pack8(ah[1], rv + 8);

    const int tt = wv;
    f32x4 R = MFMA(LDF(F_WIH + (tt * 3 + 0) * 512), gx[0].h, zf4);
    R = MFMA(LDF(F_WIH + (tt * 3 + 1) * 512), gx[1].h, R);
    R = MFMA(LDF(F_WIH + (tt * 3 + 2) * 512), px.h, R);
    R = MFMA(LDF(F_WHH + (tt * 2 + 0) * 512), ah[0].h, R);
    R = MFMA(LDF(F_WHH + (tt * 2 + 1) * 512), ah[1].h, R);
    f32x4 Z = MFMA(LDF(F_WIH + ((4 + tt) * 3 + 0) * 512), gx[0].h, zf4);
    Z = MFMA(LDF(F_WIH + ((4 + tt) * 3 + 1) * 512), gx[1].h, Z);
    Z = MFMA(LDF(F_WIH + ((4 + tt) * 3 + 2) * 512), px.h, Z);
    Z = MFMA(LDF(F_WHH + ((4 + tt) * 2 + 0) * 512), ah[0].h, Z);
    Z = MFMA(LDF(F_WHH + ((4 + tt) * 2 + 1) * 512), ah[1].h, Z);
    f32x4 Ni = MFMA(LDF(F_WIH + ((8 + tt) * 3 + 0) * 512), gx[0].h, zf4);
    Ni = MFMA(LDF(F_WIH + ((8 + tt) * 3 + 1) * 512), gx[1].h, Ni);
    Ni = MFMA(LDF(F_WIH + ((8 + tt) * 3 + 2) * 512), px.h, Ni);
    f32x4 Nh = MFMA(LDF(F_WHH + ((8 + tt) * 2 + 0) * 512), ah[0].h, zf4);
    Nh = MFMA(LDF(F_WHH + ((8 + tt) * 2 + 1) * 512), ah[1].h, Nh);
    float nsv[4];
    #pragma unroll
    for (int i = 0; i < 4; i++) {
      const int K = (tt >> 1) * 32 + (tt & 1) * 4 + i;
      const int d = q * 8 + K;
      float rr = 1.f / (1.f + expf(-(R[i] + bih[d] + bhh[d])));
      float zz = 1.f / (1.f + expf(-(Z[i] + bih[64 + d] + bhh[64 + d])));
      float ng = tanhf(Ni[i] + bih[128 + d] + rr * (Nh[i] + bhh[128 + d]));
      float st = rv[(tt >> 1) * 8 + (tt & 1) * 4 + i];
      float v = (1.f - zz) * ng + zz * st;
      out[(size_t)B * 48 + (size_t)bb * 64 + d] = v;
      nsv[i] = v;
    }
    const int dw = (tt >> 1) * 4 + (tt & 1) * 2;
    nsx[lane][dw]     = pk2(nsv[0], nsv[1]);
    nsx[lane][dw + 1] = pk2(nsv[2], nsv[3]);
  }
  __syncthreads();

  // ================= heads + pointer =================
  {
    FU an0, an1;
    an0.u = *(const u32x4*)&nsx[lane][0];
    an1.u = *(const u32x4*)&nsx[lane][4];
    float qv[16];
    #pragma unroll
    for (int mb = 0; mb < 4; mb++) {
      f32x4 Qc = MFMA(LDF(F_PQ + (mb * 2 + 0) * 512), an0.h, zf4);
      Qc = MFMA(LDF(F_PQ + (mb * 2 + 1) * 512), an1.h, Qc);
      #pragma unroll
      for (int i = 0; i < 4; i++) qv[mb * 4 + i] = Qc[i] + pqb[mb * 16 + q * 4 + i];
    }
    float qb = 0.f;
    #pragma unroll
    for (int mb = 0; mb < 4; mb++)
      #pragma unroll
      for (int i = 0; i < 4; i++) qb += qv[mb * 4 + i] * pkb[mb * 16 + q * 4 + i];
    qb += __shfl_xor(qb, 16, 64); qb += __shfl_xor(qb, 32, 64);

    if (wv < 2) {
      f32x4 L = MFMA(LDF(F_PACK + (wv * 2 + 0) * 512), an0.h, zf4);
      L = MFMA(LDF(F_PACK + (wv * 2 + 1) * 512), an1.h, L);
      #pragma unroll
      for (int i = 0; i < 4; i++) {
        int o = wv * 16 + q * 4 + i;
        if (o < 8)       out[(size_t)bb * 8 + o] = L[i] + opb[o];
        else if (o < 18) out[(size_t)B * 8 + (size_t)bb * 10 + (o - 8)] = L[i] + c1b[o - 8];
        else if (o < 28) out[(size_t)B * 18 + (size_t)bb * 10 + (o - 18)] = L[i] + c2b[o - 18];
      }
    }
    bf16x8 pkA[4][2];
    #pragma unroll
    for (int mb = 0; mb < 4; mb++) {
      pkA[mb][0] = LDF(F_PK + (mb * 2 + 0) * 512);
      pkA[mb][1] = LDF(F_PK + (mb * 2 + 1) * 512);
    }
    #pragma unroll
    for (int t = 0; t < 5; t++) {
      const int n = wv + 4 * t;
      if (n < Mcap) {
        float dt = 0.f;
        #pragma unroll
        for (int mb = 0; mb < 4; mb++) {
          f32x4 Kc = MFMA(pkA[mb][0], hA[t][0].h, zf4);
          Kc = MFMA(pkA[mb][1], hA[t][1].h, Kc);
          #pragma unroll
          for (int i = 0; i < 4; i++) dt += qv[mb * 4 + i] * Kc[i];
        }
        dt += __shfl_xor(dt, 16, 64); dt += __shfl_xor(dt, 32, 64);
        if (q == 0)
          out[(size_t)B * 28 + (size_t)bb * 20 + n] = (n < nnv) ? (dt + qb) : -1e9f;
      } else {
        if (q == 0)
          out[(size_t)B * 28 + (size_t)bb * 20 + n] = -1e9f;
      }
    }
  }
}

extern "C" void kernel_launch(void* const* d_in, const int* in_sizes, int n_in,
                              void* d_out, int out_size, void* d_ws, size_t ws_size,
                              hipStream_t stream)
{
  (void)n_in; (void)out_size; (void)ws_size;
  const float* nf   = (const float*)d_in[0];
  const int*   nnp  = (const int*)  d_in[1];
  const float* rnn  = (const float*)d_in[2];
  const float* poh  = (const float*)d_in[3];
  const float* ne_w = (const float*)d_in[4];
  const float* ne_b = (const float*)d_in[5];
  const float* m1w1 = (const float*)d_in[6];
  const float* m1b1 = (const float*)d_in[7];
  const float* m1w2 = (const float*)d_in[8];
  const float* m1b2 = (const float*)d_in[9];
  const float* n1g  = (const float*)d_in[10];
  const float* n1b  = (const float*)d_in[11];
  const float* m2w1 = (const float*)d_in[12];
  const float* m2b1 = (const float*)d_in[13];
  const float* m2w2 = (const float*)d_in[14];
  const float* m2b2 = (const float*)d_in[15];
  const float* n2g  = (const float*)d_in[16];
  const float* n2b  = (const float*)d_in[17];
  const float* wih  = (const float*)d_in[18];
  const float* whh  = (const float*)d_in[19];
  const float* bih  = (const float*)d_in[20];
  const float* bhh  = (const float*)d_in[21];
  const float* opw  = (const float*)d_in[22];
  const float* opb  = (const float*)d_in[23];
  const float* c1w  = (const float*)d_in[24];
  const float* c1b  = (const float*)d_in[25];
  const float* c2w  = (const float*)d_in[26];
  const float* c2b  = (const float*)d_in[27];
  const float* pqw  = (const float*)d_in[28];
  const float* pqb  = (const float*)d_in[29];
  const float* pkw  = (const float*)d_in[30];
  const float* pkb  = (const float*)d_in[31];
  float* out = (float*)d_out;
  const int B = in_sizes[1];
  int* ws = (int*)d_ws;   // [0..31] hist, [32..63] cursor, [64..64+B) perm, [64+B..64+2B) nn

  prep_frag<<<132, 256, 0, stream>>>(ne_w, m1w1, m1w2, m2w1, m2w2,
                                     wih, whh, pqw, opw, c1w, c2w, pkw,
                                     ne_b, m1b1, m1b2, n1g, n1b,
                                     m2b1, m2b2, n2g, n2b, ws);
  sort_hist<<<(B + 255) / 256, 256, 0, stream>>>(nnp, ws, B);
  sort_scan<<<1, 64, 0, stream>>>(ws);
  sort_scatter<<<(B + 255) / 256, 256, 0, stream>>>(nnp, ws, B);
  msp<<<B / 16, 256, 0, stream>>>(nf, ws, rnn, poh,
                                  bih, bhh, opb, c1b, c2b,
                                  pqb, pkb, out, B);
}

// Round 9
// 728.857 us; speedup vs baseline: 1.0635x; 1.0635x over previous
//
#include <hip/hip_runtime.h>
#include <hip/hip_bf16.h>
#include <cstdint>

#define NM 20
#define SB 64   // sort blocks

typedef __attribute__((ext_vector_type(8))) short bf16x8;
typedef __attribute__((ext_vector_type(4))) float f32x4;
typedef __attribute__((ext_vector_type(4))) unsigned int u32x4;

union FU { bf16x8 h; u32x4 u; };

#define MFMA(A, Bf, C) __builtin_amdgcn_mfma_f32_16x16x32_bf16((A), (Bf), (C), 0, 0, 0)

// A-fragment-packed, ROW-PERMUTED weights (bf16), built by prep each launch.
#define F_NE    0
#define F_M1W1  2048
#define F_M1W2  10240
#define F_M2W1  14336
#define F_M2W2  22528
#define F_WIH   26624
#define F_WHH   45056
#define F_PQ    57344
#define F_PK    61440
#define F_PACK  65536
#define F_BNE   67584
#define F_B11   67648
#define F_B12   67712
#define F_G1    67776
#define F_L1    67840
#define F_B21   67904
#define F_B22   67968
#define F_G2    68032
#define F_L2    68096
#define F_TOTAL 68160

// ws layout (ints): [0..1279] blockhist, [1280..2559] blockbase,
//                   [2560..2560+B) perm, [2560+B..2560+2B) nn-sorted
#define WS_HIST 0
#define WS_BASE 1280
#define WS_PERM 2560

__device__ __align__(16) short g_fr[F_TOTAL];

__device__ __forceinline__ short bf16rn(float x) {
  unsigned u = __float_as_uint(x);
  u += 0x7fffu + ((u >> 16) & 1u);
  return (short)(u >> 16);
}
__device__ __forceinline__ float bf2f(short s) {
  return __uint_as_float(((unsigned)(unsigned short)s) << 16);
}
__device__ __forceinline__ unsigned pk2(float lo, float hi) {
  __hip_bfloat162 t = __float22bfloat162_rn(float2{lo, hi});
  return *reinterpret_cast<unsigned*>(&t);
}
__device__ __forceinline__ int s64(int r) {
  int mb = r >> 4, qq = (r >> 2) & 3, i = r & 3;
  return (mb >> 1) * 32 + qq * 8 + (mb & 1) * 4 + i;
}

#define LDF(off) (*(const bf16x8*)(g_fr + (off) + lane * 8))
#define LDB(off, c) (*(const bf16x8*)(g_fr + (off) + (c) * 32 + q * 8))

// ---------------- prep ----------------
#define BUILDA(OFS, MB, KC, ROWX, GET)                                 \
  for (int idx = t; idx < (MB) * (KC) * 512; idx += T) {               \
    int j = idx & 7, ln = (idx >> 3) & 63, f = idx >> 9;               \
    int mb = f / (KC), kc = f % (KC);                                  \
    int m = mb * 16 + (ln & 15);                                       \
    int k = kc * 32 + (ln >> 4) * 8 + j;                               \
    int row = (ROWX);                                                  \
    (void)row; (void)k; (void)m;                                       \
    g_fr[(OFS) + idx] = bf16rn(GET);                                   \
  }

__global__ void __launch_bounds__(256)
prep_frag(const float* __restrict__ ne_w,
          const float* __restrict__ m1w1, const float* __restrict__ m1w2,
          const float* __restrict__ m2w1, const float* __restrict__ m2w2,
          const float* __restrict__ wih,  const float* __restrict__ whh,
          const float* __restrict__ pqw,  const float* __restrict__ opw,
          const float* __restrict__ c1w,  const float* __restrict__ c2w,
          const float* __restrict__ pkw,
          const float* __restrict__ ne_b,
          const float* __restrict__ m1b1, const float* __restrict__ m1b2,
          const float* __restrict__ n1g,  const float* __restrict__ n1b,
          const float* __restrict__ m2b1, const float* __restrict__ m2b2,
          const float* __restrict__ n2g,  const float* __restrict__ n2b)
{
  const int t = blockIdx.x * blockDim.x + threadIdx.x;
  const int T = gridDim.x * blockDim.x;
  BUILDA(F_NE,   4, 1, s64(m), (k < 16 ? ne_w[row * 16 + k] : 0.f))
  BUILDA(F_M1W1, 4, 4, s64(m), m1w1[row * 128 + k])
  BUILDA(F_M1W2, 4, 2, s64(m), m1w2[row * 64 + k])
  BUILDA(F_M2W1, 4, 4, s64(m), m2w1[row * 128 + k])
  BUILDA(F_M2W2, 4, 2, s64(m), m2w2[row * 64 + k])
  BUILDA(F_WIH, 12, 3, (m & 0xC0) | s64(m & 63), (k < 72 ? wih[row * 72 + k] : 0.f))
  BUILDA(F_WHH, 12, 2, (m & 0xC0) | s64(m & 63), whh[row * 64 + k])
  BUILDA(F_PQ,   4, 2, m, pqw[row * 64 + k])
  BUILDA(F_PK,   4, 2, m, pkw[row * 64 + k])
  BUILDA(F_PACK, 2, 2, m, (row < 8 ? opw[row * 64 + k]
                           : row < 18 ? c1w[(row - 8) * 64 + k]
                           : row < 28 ? c2w[(row - 18) * 64 + k] : 0.f))
  for (int i = t; i < 64; i += T) {
    g_fr[F_BNE + i] = bf16rn(ne_b[i]);
    g_fr[F_B11 + i] = bf16rn(m1b1[i]);
    g_fr[F_B12 + i] = bf16rn(m1b2[i]);
    g_fr[F_G1  + i] = bf16rn(n1g[i]);
    g_fr[F_L1  + i] = bf16rn(n1b[i]);
    g_fr[F_B21 + i] = bf16rn(m2b1[i]);
    g_fr[F_B22 + i] = bf16rn(m2b2[i]);
    g_fr[F_G2  + i] = bf16rn(n2g[i]);
    g_fr[F_L2  + i] = bf16rn(n2b[i]);
  }
}

// ---------------- hierarchical counting sort (NO global atomics) ----------------
__global__ void __launch_bounds__(256)
sort_hist(const int* __restrict__ nnp, int* __restrict__ ws, int B) {
  __shared__ int lh[NM];
  if (threadIdx.x < NM) lh[threadIdx.x] = 0;
  __syncthreads();
  const int per = B / SB;
  const int base = blockIdx.x * per;
  for (int i = threadIdx.x; i < per; i += 256)
    atomicAdd(&lh[nnp[base + i] - 1], 1);
  __syncthreads();
  if (threadIdx.x < NM) ws[WS_HIST + blockIdx.x * NM + threadIdx.x] = lh[threadIdx.x];
}

__global__ void __launch_bounds__(64)
sort_scan(int* __restrict__ ws) {
  const int lane = threadIdx.x;
  int tot = 0;
  if (lane < NM)
    for (int b = 0; b < SB; b++) tot += ws[WS_HIST + b * NM + lane];
  // exclusive prefix over bins (lanes 0..19)
  int pre = tot;
  #pragma unroll
  for (int d = 1; d < 32; d <<= 1) {
    int v = __shfl_up(pre, d, 64);
    if (lane >= d) pre += v;
  }
  int acc = pre - tot;
  if (lane < NM)
    for (int b = 0; b < SB; b++) {
      int c = ws[WS_HIST + b * NM + lane];
      ws[WS_BASE + b * NM + lane] = acc;
      acc += c;
    }
}

__global__ void __launch_bounds__(256)
sort_scatter(const int* __restrict__ nnp, int* __restrict__ ws, int B) {
  __shared__ int cur[NM];
  if (threadIdx.x < NM) cur[threadIdx.x] = ws[WS_BASE + blockIdx.x * NM + threadIdx.x];
  __syncthreads();
  const int per = B / SB;
  const int base = blockIdx.x * per;
  for (int i = threadIdx.x; i < per; i += 256) {
    int b = base + i;
    int nn = nnp[b];
    int pos = atomicAdd(&cur[nn - 1], 1);   // LDS atomic
    ws[WS_PERM + pos] = b;
    ws[WS_PERM + B + pos] = nn;
  }
}

__device__ __forceinline__ void pack8(FU& f, const float* v) {
  f.u[0] = pk2(v[0], v[1]); f.u[1] = pk2(v[2], v[3]);
  f.u[2] = pk2(v[4], v[5]); f.u[3] = pk2(v[6], v[7]);
}

// ---------------- MP stage: nodes n = wv + 4t, capped at Mcap ----------------
__device__ __forceinline__ void mp_stage(
    FU hA[][2], float* macc_out, const FU* msgf,
    int w1off, int w2off, int b1o, int b2o, int lgo, int lbo,
    int nnv, int Mcap, int wv, int lane, int q)
{
  const f32x4 zf4 = {0.f, 0.f, 0.f, 0.f};
  bf16x8 w1A[4][2], w2A[4][2];
  #pragma unroll
  for (int mb = 0; mb < 4; mb++) {
    w1A[mb][0] = LDF(w1off + (mb * 4 + 0) * 512);
    w1A[mb][1] = LDF(w1off + (mb * 4 + 1) * 512);
    w2A[mb][0] = LDF(w2off + (mb * 2 + 0) * 512);
    w2A[mb][1] = LDF(w2off + (mb * 2 + 1) * 512);
  }
  f32x4 tmsg[4];
  #pragma unroll
  for (int mb = 0; mb < 4; mb++) {
    tmsg[mb] = MFMA(LDF(w1off + (mb * 4 + 2) * 512), msgf[0].h, zf4);
    tmsg[mb] = MFMA(LDF(w1off + (mb * 4 + 3) * 512), msgf[1].h, tmsg[mb]);
  }
  FU b1p[2], b2p[2], lgp[2], lbp[2];
  #pragma unroll
  for (int c = 0; c < 2; c++) {
    b1p[c].h = LDB(b1o, c); b2p[c].h = LDB(b2o, c);
    lgp[c].h = LDB(lgo, c); lbp[c].h = LDB(lbo, c);
  }

  #pragma unroll
  for (int t = 0; t < 5; t++) {
    const int n = wv + 4 * t;
    if (n >= Mcap) break;
    f32x4 T[4];
    #pragma unroll
    for (int mb = 0; mb < 4; mb++) {
      T[mb] = MFMA(w1A[mb][0], hA[t][0].h, tmsg[mb]);
      T[mb] = MFMA(w1A[mb][1], hA[t][1].h, T[mb]);
    }
    FU tb[2];
    #pragma unroll
    for (int c = 0; c < 2; c++)
      #pragma unroll
      for (int w = 0; w < 4; w++) {
        int mb = 2 * c + (w >> 1), i0 = (w & 1) * 2;
        float blo = bf2f(b1p[mb >> 1].h[(mb & 1) * 4 + i0]);
        float bhi = bf2f(b1p[mb >> 1].h[(mb & 1) * 4 + i0 + 1]);
        float lo = fmaxf(T[mb][i0]     + blo, 0.f);
        float hi = fmaxf(T[mb][i0 + 1] + bhi, 0.f);
        tb[c].u[w] = pk2(lo, hi);
      }
    f32x4 H[4];
    #pragma unroll
    for (int mb = 0; mb < 4; mb++) {
      H[mb] = MFMA(w2A[mb][0], tb[0].h, zf4);
      H[mb] = MFMA(w2A[mb][1], tb[1].h, H[mb]);
    }
    float y[16]; float s = 0.f, ss = 0.f;
    #pragma unroll
    for (int k = 0; k < 16; k++) {
      int c = k >> 3, j = k & 7;
      float v = H[2 * c + (j >> 2)][j & 3] + bf2f(b2p[c].h[j]) + bf2f(hA[t][c].h[j]);
      y[k] = v; s += v; ss += v * v;
    }
    s += __shfl_xor(s, 16, 64); ss += __shfl_xor(ss, 16, 64);
    s += __shfl_xor(s, 32, 64); ss += __shfl_xor(ss, 32, 64);
    float mu = s * 0.015625f;
    float rstd = rsqrtf(ss * 0.015625f - mu * mu + 1e-5f);
    float mfv = (n < nnv) ? 1.f : 0.f;
    #pragma unroll
    for (int k = 0; k < 16; k++) {
      int c = k >> 3, j = k & 7;
      float hv = ((y[k] - mu) * rstd * bf2f(lgp[c].h[j]) + bf2f(lbp[c].h[j])) * mfv;
      macc_out[k] += hv; y[k] = hv;
    }
    pack8(hA[t][0], y); pack8(hA[t][1], y + 8);
  }
}

// ---------------- main: 16 sorted batches / block ----------------
__global__ void __launch_bounds__(256, 3)
msp(const float* __restrict__ nf, const int* __restrict__ wsp,
    const float* __restrict__ rnn, const float* __restrict__ poh,
    const float* __restrict__ bih, const float* __restrict__ bhh,
    const float* __restrict__ opb, const float* __restrict__ c1b,
    const float* __restrict__ c2b, const float* __restrict__ pqb,
    const float* __restrict__ pkb,
    float* __restrict__ out, int B)
{
  __shared__ __align__(16) float exch[2][4][64][17];
  __shared__ __align__(16) unsigned nsx[64][8];

  const int tid = threadIdx.x;
  const int wv = tid >> 6;
  const int lane = tid & 63;
  const int l15 = lane & 15, q = lane >> 4;
  const int pos = blockIdx.x * 16 + l15;

  const int bb  = wsp[WS_PERM + pos];
  const int nnv = wsp[WS_PERM + B + pos];
  int mx = nnv;
  mx = max(mx, __shfl_xor(mx, 1, 64));
  mx = max(mx, __shfl_xor(mx, 2, 64));
  mx = max(mx, __shfl_xor(mx, 4, 64));
  mx = max(mx, __shfl_xor(mx, 8, 64));
  const int Mcap = mx;

  // HOISTED rnn gather: in flight during the whole MP phase
  const float* rr0 = rnn + (size_t)bb * 64;
  float4 rva = *(const float4*)(rr0 + q * 8);
  float4 rvb = *(const float4*)(rr0 + q * 8 + 4);
  float4 rvc = *(const float4*)(rr0 + 32 + q * 8);
  float4 rvd = *(const float4*)(rr0 + 32 + q * 8 + 4);

  const float inv = 1.0f / (float)nnv;
  const f32x4 zf4 = {0.f, 0.f, 0.f, 0.f};

  FU hA[5][2];
  float mac[16];
  #pragma unroll
  for (int k = 0; k < 16; k++) mac[k] = 0.f;

  // ================= E =================
  {
    bf16x8 neA[4];
    #pragma unroll
    for (int mb = 0; mb < 4; mb++) neA[mb] = LDF(F_NE + mb * 512);
    FU nep[2];
    nep[0].h = LDB(F_BNE, 0); nep[1].h = LDB(F_BNE, 1);
    #pragma unroll
    for (int t = 0; t < 5; t++) {
      const int n = wv + 4 * t;
      if (n >= Mcap) break;
      FU bx;
      if (q < 2) {
        const float* p = nf + ((size_t)bb * NM + n) * 16 + q * 8;
        float4 x0 = *(const float4*)p, x1 = *(const float4*)(p + 4);
        bx.u[0] = pk2(x0.x, x0.y); bx.u[1] = pk2(x0.z, x0.w);
        bx.u[2] = pk2(x1.x, x1.y); bx.u[3] = pk2(x1.z, x1.w);
      } else {
        bx.u[0] = 0; bx.u[1] = 0; bx.u[2] = 0; bx.u[3] = 0;
      }
      f32x4 C[4];
      #pragma unroll
      for (int mb = 0; mb < 4; mb++) C[mb] = MFMA(neA[mb], bx.h, zf4);
      float hv[16];
      #pragma unroll
      for (int k = 0; k < 16; k++) {
        int c = k >> 3, j = k & 7;
        hv[k] = C[2 * c + (j >> 2)][j & 3] + bf2f(nep[c].h[j]);
        if (n < nnv) mac[k] += hv[k];
      }
      pack8(hA[t][0], hv); pack8(hA[t][1], hv + 8);
    }
  }

  FU msgf[2];
  float tmp[16];
  #define EXCHANGE(REG)                                                        \
    _Pragma("unroll")                                                          \
    for (int k = 0; k < 16; k++) exch[REG][wv][lane][k] = mac[k];              \
    __syncthreads();                                                           \
    _Pragma("unroll")                                                          \
    for (int k = 0; k < 16; k++)                                               \
      tmp[k] = (exch[REG][0][lane][k] + exch[REG][1][lane][k] +                \
                exch[REG][2][lane][k] + exch[REG][3][lane][k]) * inv;

  EXCHANGE(0)
  pack8(msgf[0], tmp); pack8(msgf[1], tmp + 8);
  #pragma unroll
  for (int k = 0; k < 16; k++) mac[k] = 0.f;
  mp_stage(hA, mac, msgf, F_M1W1, F_M1W2, F_B11, F_B12, F_G1, F_L1, nnv, Mcap, wv, lane, q);

  EXCHANGE(1)
  pack8(msgf[0], tmp); pack8(msgf[1], tmp + 8);
  #pragma unroll
  for (int k = 0; k < 16; k++) mac[k] = 0.f;
  mp_stage(hA, mac, msgf, F_M2W1, F_M2W2, F_B21, F_B22, F_G2, F_L2, nnv, Mcap, wv, lane, q);

  // poh gather issued before the final exchange barrier
  FU px;
  if (q == 0) {
    const float* pp = poh + (size_t)bb * 8;
    float4 p0 = *(const float4*)pp, p1 = *(const float4*)(pp + 4);
    px.u[0] = pk2(p0.x, p0.y); px.u[1] = pk2(p0.z, p0.w);
    px.u[2] = pk2(p1.x, p1.y); px.u[3] = pk2(p1.z, p1.w);
  } else { px.u[0] = 0; px.u[1] = 0; px.u[2] = 0; px.u[3] = 0; }

  EXCHANGE(0)   // graph_vec

  // ================= GRU: wave wv owns gate tile tt = wv =================
  {
    FU gx[2]; pack8(gx[0], tmp); pack8(gx[1], tmp + 8);
    float rv[16];
    rv[0] = rva.x; rv[1] = rva.y; rv[2] = rva.z; rv[3] = rva.w;
    rv[4] = rvb.x; rv[5] = rvb.y; rv[6] = rvb.z; rv[7] = rvb.w;
    rv[8] = rvc.x; rv[9] = rvc.y; rv[10] = rvc.z; rv[11] = rvc.w;
    rv[12] = rvd.x; rv[13] = rvd.y; rv[14] = rvd.z; rv[15] = rvd.w;
    FU ah[2]; pack8(ah[0], rv); pack8(ah[1], rv + 8);

    const int tt = wv;
    f32x4 R = MFMA(LDF(F_WIH + (tt * 3 + 0) * 512), gx[0].h, zf4);
    R = MFMA(LDF(F_WIH + (tt * 3 + 1) * 512), gx[1].h, R);
    R = MFMA(LDF(F_WIH + (tt * 3 + 2) * 512), px.h, R);
    R = MFMA(LDF(F_WHH + (tt * 2 + 0) * 512), ah[0].h, R);
    R = MFMA(LDF(F_WHH + (tt * 2 + 1) * 512), ah[1].h, R);
    f32x4 Z = MFMA(LDF(F_WIH + ((4 + tt) * 3 + 0) * 512), gx[0].h, zf4);
    Z = MFMA(LDF(F_WIH + ((4 + tt) * 3 + 1) * 512), gx[1].h, Z);
    Z = MFMA(LDF(F_WIH + ((4 + tt) * 3 + 2) * 512), px.h, Z);
    Z = MFMA(LDF(F_WHH + ((4 + tt) * 2 + 0) * 512), ah[0].h, Z);
    Z = MFMA(LDF(F_WHH + ((4 + tt) * 2 + 1) * 512), ah[1].h, Z);
    f32x4 Ni = MFMA(LDF(F_WIH + ((8 + tt) * 3 + 0) * 512), gx[0].h, zf4);
    Ni = MFMA(LDF(F_WIH + ((8 + tt) * 3 + 1) * 512), gx[1].h, Ni);
    Ni = MFMA(LDF(F_WIH + ((8 + tt) * 3 + 2) * 512), px.h, Ni);
    f32x4 Nh = MFMA(LDF(F_WHH + ((8 + tt) * 2 + 0) * 512), ah[0].h, zf4);
    Nh = MFMA(LDF(F_WHH + ((8 + tt) * 2 + 1) * 512), ah[1].h, Nh);
    float nsv[4];
    #pragma unroll
    for (int i = 0; i < 4; i++) {
      const int K = (tt >> 1) * 32 + (tt & 1) * 4 + i;
      const int d = q * 8 + K;
      float rr = 1.f / (1.f + expf(-(R[i] + bih[d] + bhh[d])));
      float zz = 1.f / (1.f + expf(-(Z[i] + bih[64 + d] + bhh[64 + d])));
      float ng = tanhf(Ni[i] + bih[128 + d] + rr * (Nh[i] + bhh[128 + d]));
      float st = rv[(tt >> 1) * 8 + (tt & 1) * 4 + i];
      float v = (1.f - zz) * ng + zz * st;
      out[(size_t)B * 48 + (size_t)bb * 64 + d] = v;
      nsv[i] = v;
    }
    const int dw = (tt >> 1) * 4 + (tt & 1) * 2;
    nsx[lane][dw]     = pk2(nsv[0], nsv[1]);
    nsx[lane][dw + 1] = pk2(nsv[2], nsv[3]);
  }
  __syncthreads();

  // ================= heads + pointer =================
  {
    FU an0, an1;
    an0.u = *(const u32x4*)&nsx[lane][0];
    an1.u = *(const u32x4*)&nsx[lane][4];
    float qv[16];
    #pragma unroll
    for (int mb = 0; mb < 4; mb++) {
      f32x4 Qc = MFMA(LDF(F_PQ + (mb * 2 + 0) * 512), an0.h, zf4);
      Qc = MFMA(LDF(F_PQ + (mb * 2 + 1) * 512), an1.h, Qc);
      #pragma unroll
      for (int i = 0; i < 4; i++) qv[mb * 4 + i] = Qc[i] + pqb[mb * 16 + q * 4 + i];
    }
    float qb = 0.f;
    #pragma unroll
    for (int mb = 0; mb < 4; mb++)
      #pragma unroll
      for (int i = 0; i < 4; i++) qb += qv[mb * 4 + i] * pkb[mb * 16 + q * 4 + i];
    qb += __shfl_xor(qb, 16, 64); qb += __shfl_xor(qb, 32, 64);

    if (wv < 2) {
      f32x4 L = MFMA(LDF(F_PACK + (wv * 2 + 0) * 512), an0.h, zf4);
      L = MFMA(LDF(F_PACK + (wv * 2 + 1) * 512), an1.h, L);
      #pragma unroll
      for (int i = 0; i < 4; i++) {
        int o = wv * 16 + q * 4 + i;
        if (o < 8)       out[(size_t)bb * 8 + o] = L[i] + opb[o];
        else if (o < 18) out[(size_t)B * 8 + (size_t)bb * 10 + (o - 8)] = L[i] + c1b[o - 8];
        else if (o < 28) out[(size_t)B * 18 + (size_t)bb * 10 + (o - 18)] = L[i] + c2b[o - 18];
      }
    }
    bf16x8 pkA[4][2];
    #pragma unroll
    for (int mb = 0; mb < 4; mb++) {
      pkA[mb][0] = LDF(F_PK + (mb * 2 + 0) * 512);
      pkA[mb][1] = LDF(F_PK + (mb * 2 + 1) * 512);
    }
    #pragma unroll
    for (int t = 0; t < 5; t++) {
      const int n = wv + 4 * t;
      if (n < Mcap) {
        float dt = 0.f;
        #pragma unroll
        for (int mb = 0; mb < 4; mb++) {
          f32x4 Kc = MFMA(pkA[mb][0], hA[t][0].h, zf4);
          Kc = MFMA(pkA[mb][1], hA[t][1].h, Kc);
          #pragma unroll
          for (int i = 0; i < 4; i++) dt += qv[mb * 4 + i] * Kc[i];
        }
        dt += __shfl_xor(dt, 16, 64); dt += __shfl_xor(dt, 32, 64);
        if (q == 0)
          out[(size_t)B * 28 + (size_t)bb * 20 + n] = (n < nnv) ? (dt + qb) : -1e9f;
      } else {
        if (q == 0)
          out[(size_t)B * 28 + (size_t)bb * 20 + n] = -1e9f;
      }
    }
  }
}

extern "C" void kernel_launch(void* const* d_in, const int* in_sizes, int n_in,
                              void* d_out, int out_size, void* d_ws, size_t ws_size,
                              hipStream_t stream)
{
  (void)n_in; (void)out_size; (void)ws_size;
  const float* nf   = (const float*)d_in[0];
  const int*   nnp  = (const int*)  d_in[1];
  const float* rnn  = (const float*)d_in[2];
  const float* poh  = (const float*)d_in[3];
  const float* ne_w = (const float*)d_in[4];
  const float* ne_b = (const float*)d_in[5];
  const float* m1w1 = (const float*)d_in[6];
  const float* m1b1 = (const float*)d_in[7];
  const float* m1w2 = (const float*)d_in[8];
  const float* m1b2 = (const float*)d_in[9];
  const float* n1g  = (const float*)d_in[10];
  const float* n1b  = (const float*)d_in[11];
  const float* m2w1 = (const float*)d_in[12];
  const float* m2b1 = (const float*)d_in[13];
  const float* m2w2 = (const float*)d_in[14];
  const float* m2b2 = (const float*)d_in[15];
  const float* n2g  = (const float*)d_in[16];
  const float* n2b  = (const float*)d_in[17];
  const float* wih  = (const float*)d_in[18];
  const float* whh  = (const float*)d_in[19];
  const float* bih  = (const float*)d_in[20];
  const float* bhh  = (const float*)d_in[21];
  const float* opw  = (const float*)d_in[22];
  const float* opb  = (const float*)d_in[23];
  const float* c1w  = (const float*)d_in[24];
  const float* c1b  = (const float*)d_in[25];
  const float* c2w  = (const float*)d_in[26];
  const float* c2b  = (const float*)d_in[27];
  const float* pqw  = (const float*)d_in[28];
  const float* pqb  = (const float*)d_in[29];
  const float* pkw  = (const float*)d_in[30];
  const float* pkb  = (const float*)d_in[31];
  float* out = (float*)d_out;
  const int B = in_sizes[1];
  int* ws = (int*)d_ws;

  prep_frag<<<132, 256, 0, stream>>>(ne_w, m1w1, m1w2, m2w1, m2w2,
                                     wih, whh, pqw, opw, c1w, c2w, pkw,
                                     ne_b, m1b1, m1b2, n1g, n1b,
                                     m2b1, m2b2, n2g, n2b);
  sort_hist<<<SB, 256, 0, stream>>>(nnp, ws, B);
  sort_scan<<<1, 64, 0, stream>>>(ws);
  sort_scatter<<<SB, 256, 0, stream>>>(nnp, ws, B);
  msp<<<B / 16, 256, 0, stream>>>(nf, ws, rnn, poh,
                                  bih, bhh, opb, c1b, c2b,
                                  pqb, pkb, out, B);
}